// Round 1
// baseline (610.080 us; speedup 1.0000x reference)
//
#include <hip/hip_runtime.h>

constexpr int CIN = 768;
constexpr int CD  = 32;
constexpr int NE  = 8192;
constexpr int M   = 16384;      // B*N = 64*256
constexpr int S   = 16;         // code-chunk splits for argmin
constexpr int CHUNK = NE / S;   // 512 codes per chunk
constexpr int PB  = 32;         // point-blocks for argmin
constexpr int PPB = M / PB;     // 512 points per block

// ---------------- codebook = emb @ W_ct + b_ct ; cnorm = ||row||^2 ----------------
__global__ void k_codebook(const float* __restrict__ emb,
                           const float* __restrict__ Wct,
                           const float* __restrict__ bct,
                           float* __restrict__ cb,
                           float* __restrict__ cnorm) {
  __shared__ float w[CD * CD];
  const int t = threadIdx.x;
  for (int i = t; i < CD * CD; i += 256) w[i] = Wct[i];
  __syncthreads();
  const int g   = blockIdx.x * 256 + t;   // grid 1024 -> 262144 elems
  const int row = g >> 5;
  const int col = g & 31;
  float acc = bct[col];
  const float* er = emb + row * CD;
  #pragma unroll
  for (int k = 0; k < CD; ++k) acc = fmaf(er[k], w[k * CD + col], acc);
  cb[g] = acc;
  float v = acc * acc;
  #pragma unroll
  for (int m = 16; m >= 1; m >>= 1) v += __shfl_xor(v, m, 64);
  if (col == 0) cnorm[row] = v;
}

// ---------------- zc = z @ W_compress + b_compress ----------------
// thread = (row, 8-col group): g = bid*256+t, row = g>>2, c0 = (g&3)*8
__global__ void k_compress(const float* __restrict__ z,
                           const float* __restrict__ Wc,
                           const float* __restrict__ bc,
                           float* __restrict__ zc) {
  const int g   = blockIdx.x * 256 + threadIdx.x;  // grid 256 -> 65536 threads
  const int row = g >> 2;
  const int c0  = (g & 3) * 8;
  float acc[8];
  #pragma unroll
  for (int j = 0; j < 8; ++j) acc[j] = bc[c0 + j];
  const float4* zr = (const float4*)(z + (long)row * CIN);
  for (int k4 = 0; k4 < CIN / 4; ++k4) {
    float4 zv = zr[k4];
    float zz[4] = {zv.x, zv.y, zv.z, zv.w};
    #pragma unroll
    for (int u = 0; u < 4; ++u) {
      const float4* w4 = (const float4*)(Wc + (k4 * 4 + u) * CD + c0);
      float4 wa = w4[0];
      float4 wb = w4[1];
      acc[0] = fmaf(zz[u], wa.x, acc[0]);
      acc[1] = fmaf(zz[u], wa.y, acc[1]);
      acc[2] = fmaf(zz[u], wa.z, acc[2]);
      acc[3] = fmaf(zz[u], wa.w, acc[3]);
      acc[4] = fmaf(zz[u], wb.x, acc[4]);
      acc[5] = fmaf(zz[u], wb.y, acc[5]);
      acc[6] = fmaf(zz[u], wb.z, acc[6]);
      acc[7] = fmaf(zz[u], wb.w, acc[7]);
    }
  }
  float4* o = (float4*)(zc + (long)row * CD + c0);
  o[0] = make_float4(acc[0], acc[1], acc[2], acc[3]);
  o[1] = make_float4(acc[4], acc[5], acc[6], acc[7]);
}

// ---------------- partial argmin over code chunk ----------------
// block handles 512 points x 512 codes; thread = 2 points (p0, p0+256)
__global__ void k_argmin(const float* __restrict__ zc,
                         const float* __restrict__ cb,
                         const float* __restrict__ cnorm,
                         float* __restrict__ pd,
                         int* __restrict__ pi) {
  const int t  = threadIdx.x;
  const int pb = blockIdx.x & (PB - 1);
  const int cs = blockIdx.x >> 5;           // grid 512
  const int p0 = pb * PPB + t;
  const int p1 = p0 + 256;
  float z0[CD], z1[CD];
  const float4* a = (const float4*)(zc + (long)p0 * CD);
  const float4* b = (const float4*)(zc + (long)p1 * CD);
  #pragma unroll
  for (int q = 0; q < 8; ++q) {
    float4 va = a[q];
    z0[4 * q + 0] = va.x; z0[4 * q + 1] = va.y; z0[4 * q + 2] = va.z; z0[4 * q + 3] = va.w;
    float4 vb = b[q];
    z1[4 * q + 0] = vb.x; z1[4 * q + 1] = vb.y; z1[4 * q + 2] = vb.z; z1[4 * q + 3] = vb.w;
  }
  const int j0 = cs * CHUNK;
  float bd0 = 1e30f, bd1 = 1e30f;
  int bj0 = j0, bj1 = j0;
  for (int j = j0; j < j0 + CHUNK; ++j) {
    const float4* c4 = (const float4*)(cb + (long)j * CD);
    float s0a = 0.f, s0b = 0.f, s1a = 0.f, s1b = 0.f;
    #pragma unroll
    for (int q = 0; q < 8; ++q) {
      float4 c = c4[q];
      s0a = fmaf(z0[4 * q + 0], c.x, s0a);
      s1a = fmaf(z1[4 * q + 0], c.x, s1a);
      s0b = fmaf(z0[4 * q + 1], c.y, s0b);
      s1b = fmaf(z1[4 * q + 1], c.y, s1b);
      s0a = fmaf(z0[4 * q + 2], c.z, s0a);
      s1a = fmaf(z1[4 * q + 2], c.z, s1a);
      s0b = fmaf(z0[4 * q + 3], c.w, s0b);
      s1b = fmaf(z1[4 * q + 3], c.w, s1b);
    }
    const float cn = cnorm[j];
    const float d0 = fmaf(-2.f, s0a + s0b, cn);
    const float d1 = fmaf(-2.f, s1a + s1b, cn);
    if (d0 < bd0) { bd0 = d0; bj0 = j; }
    if (d1 < bd1) { bd1 = d1; bj1 = j; }
  }
  pd[cs * M + p0] = bd0;
  pd[cs * M + p1] = bd1;
  pi[cs * M + p0] = bj0;
  pi[cs * M + p1] = bj1;
}

// ---------------- combine partial argmins, gather z_q, loss partials ----------------
__global__ void k_combine(const float* __restrict__ zc,
                          const float* __restrict__ cb,
                          const float* __restrict__ pd,
                          const int* __restrict__ pi,
                          float* __restrict__ zq,
                          float* __restrict__ lpart) {
  const int t = threadIdx.x;
  const int p = blockIdx.x * 256 + t;   // grid 64
  float bd = 1e30f;
  int bj = 0;
  for (int s = 0; s < S; ++s) {
    float d = pd[s * M + p];
    int   i = pi[s * M + p];
    if (d < bd) { bd = d; bj = i; }
  }
  const float4* c4 = (const float4*)(cb + (long)bj * CD);
  const float4* z4 = (const float4*)(zc + (long)p * CD);
  float4* q4 = (float4*)(zq + (long)p * CD);
  float ls = 0.f;
  #pragma unroll
  for (int q = 0; q < 8; ++q) {
    float4 c = c4[q];
    float4 zz = z4[q];
    q4[q] = c;
    float dx = c.x - zz.x, dy = c.y - zz.y, dz = c.z - zz.z, dw = c.w - zz.w;
    ls += dx * dx + dy * dy + dz * dz + dw * dw;
  }
  #pragma unroll
  for (int m = 32; m >= 1; m >>= 1) ls += __shfl_xor(ls, m, 64);
  __shared__ float red[4];
  if ((t & 63) == 0) red[t >> 6] = ls;
  __syncthreads();
  if (t == 0) lpart[blockIdx.x] = red[0] + red[1] + red[2] + red[3];
}

__global__ void k_loss(const float* __restrict__ lpart, float* __restrict__ out_loss) {
  float v = (threadIdx.x < 64) ? lpart[threadIdx.x] : 0.f;
  #pragma unroll
  for (int m = 32; m >= 1; m >>= 1) v += __shfl_xor(v, m, 64);
  if (threadIdx.x == 0) *out_loss = 3.0f * v / (float)(M * CD);
}

// ---------------- out = z_q @ W_expand + b_expand ----------------
// block = 32 rows; thread owns cols {t, t+256, t+512}, W cols in regs
__global__ void k_expand(const float* __restrict__ zq,
                         const float* __restrict__ We,
                         const float* __restrict__ be,
                         float* __restrict__ out) {
  const int t = threadIdx.x;
  const int r0 = blockIdx.x * 32;   // grid 512
  float w[CD][3];
  #pragma unroll
  for (int k = 0; k < CD; ++k) {
    w[k][0] = We[k * CIN + t];
    w[k][1] = We[k * CIN + t + 256];
    w[k][2] = We[k * CIN + t + 512];
  }
  const float b0 = be[t], b1 = be[t + 256], b2 = be[t + 512];
  for (int r = r0; r < r0 + 32; ++r) {
    const float4* q4 = (const float4*)(zq + (long)r * CD);
    float a0 = b0, a1 = b1, a2 = b2;
    #pragma unroll
    for (int k4 = 0; k4 < 8; ++k4) {
      float4 qv = q4[k4];
      a0 = fmaf(qv.x, w[4 * k4 + 0][0], a0);
      a1 = fmaf(qv.x, w[4 * k4 + 0][1], a1);
      a2 = fmaf(qv.x, w[4 * k4 + 0][2], a2);
      a0 = fmaf(qv.y, w[4 * k4 + 1][0], a0);
      a1 = fmaf(qv.y, w[4 * k4 + 1][1], a1);
      a2 = fmaf(qv.y, w[4 * k4 + 1][2], a2);
      a0 = fmaf(qv.z, w[4 * k4 + 2][0], a0);
      a1 = fmaf(qv.z, w[4 * k4 + 2][1], a1);
      a2 = fmaf(qv.z, w[4 * k4 + 2][2], a2);
      a0 = fmaf(qv.w, w[4 * k4 + 3][0], a0);
      a1 = fmaf(qv.w, w[4 * k4 + 3][1], a1);
      a2 = fmaf(qv.w, w[4 * k4 + 3][2], a2);
    }
    float* o = out + (long)r * CIN;
    o[t]       = a0;
    o[t + 256] = a1;
    o[t + 512] = a2;
  }
}

extern "C" void kernel_launch(void* const* d_in, const int* in_sizes, int n_in,
                              void* d_out, int out_size, void* d_ws, size_t ws_size,
                              hipStream_t stream) {
  const float* z   = (const float*)d_in[0];
  const float* emb = (const float*)d_in[1];
  const float* Wc  = (const float*)d_in[2];
  const float* bc  = (const float*)d_in[3];
  const float* Wct = (const float*)d_in[4];
  const float* bct = (const float*)d_in[5];
  const float* We  = (const float*)d_in[6];
  const float* be  = (const float*)d_in[7];
  float* out = (float*)d_out;

  float* cb    = (float*)d_ws;          // NE*CD    = 262144
  float* cnorm = cb + NE * CD;          // NE       = 8192
  float* zc    = cnorm + NE;            // M*CD     = 524288
  float* pd    = zc + M * CD;           // S*M      = 262144
  float* zq    = pd + S * M;            // M*CD     = 524288
  float* lpart = zq + M * CD;           // 64
  int*   pi    = (int*)(lpart + 64);    // S*M      = 262144

  k_codebook<<<NE * CD / 256, 256, 0, stream>>>(emb, Wct, bct, cb, cnorm);
  k_compress<<<M * 4 / 256, 256, 0, stream>>>(z, Wc, bc, zc);
  k_argmin<<<PB * S, 256, 0, stream>>>(zc, cb, cnorm, pd, pi);
  k_combine<<<M / 256, 256, 0, stream>>>(zc, cb, pd, pi, zq, lpart);
  k_loss<<<1, 64, 0, stream>>>(lpart, out + (long)M * CIN);
  k_expand<<<M / 32, 256, 0, stream>>>(zq, We, be, out);
}

// Round 2
// 447.826 us; speedup vs baseline: 1.3623x; 1.3623x over previous
//
#include <hip/hip_runtime.h>

constexpr int CIN = 768;
constexpr int CD  = 32;
constexpr int NE  = 8192;
constexpr int M   = 16384;      // B*N = 64*256
constexpr int S   = 16;         // code-chunk splits for argmin
constexpr int CHUNK = NE / S;   // 512 codes per chunk
constexpr int PB  = 32;         // point-blocks for argmin
constexpr int PPB = M / PB;     // 512 points per block

// ---------------- codebook = emb @ W_ct + b_ct ; cnorm = ||row||^2 ----------------
__global__ void k_codebook(const float* __restrict__ emb,
                           const float* __restrict__ Wct,
                           const float* __restrict__ bct,
                           float* __restrict__ cb,
                           float* __restrict__ cnorm) {
  __shared__ float w[CD * CD];
  const int t = threadIdx.x;
  for (int i = t; i < CD * CD; i += 256) w[i] = Wct[i];
  __syncthreads();
  const int g   = blockIdx.x * 256 + t;   // grid 1024 -> 262144 elems
  const int row = g >> 5;
  const int col = g & 31;
  float acc = bct[col];
  const float* er = emb + row * CD;
  #pragma unroll
  for (int k = 0; k < CD; ++k) acc = fmaf(er[k], w[k * CD + col], acc);
  cb[g] = acc;
  float v = acc * acc;
  #pragma unroll
  for (int m = 16; m >= 1; m >>= 1) v += __shfl_xor(v, m, 64);
  if (col == 0) cnorm[row] = v;
}

// ---------------- zc = z @ W_compress + b_compress ----------------
// block = 256 threads = 32 cols x 8 row-lanes; 4 rows/thread -> 32 rows/block
__global__ void k_compress(const float* __restrict__ z,
                           const float* __restrict__ Wc,
                           const float* __restrict__ bc,
                           float* __restrict__ zc) {
  const int t  = threadIdx.x;
  const int c  = t & 31;
  const int rl = t >> 5;                 // 0..7
  const int r0 = blockIdx.x * 32;        // grid 512
  float acc[4];
  #pragma unroll
  for (int i = 0; i < 4; ++i) acc[i] = bc[c];
  #pragma unroll 4
  for (int k4 = 0; k4 < CIN / 4; ++k4) {
    float4 zr[4];
    #pragma unroll
    for (int i = 0; i < 4; ++i)
      zr[i] = ((const float4*)(z + (long)(r0 + rl + 8 * i) * CIN))[k4];
    const float w0 = Wc[(k4 * 4 + 0) * CD + c];
    const float w1 = Wc[(k4 * 4 + 1) * CD + c];
    const float w2 = Wc[(k4 * 4 + 2) * CD + c];
    const float w3 = Wc[(k4 * 4 + 3) * CD + c];
    #pragma unroll
    for (int i = 0; i < 4; ++i) {
      acc[i] = fmaf(zr[i].x, w0, acc[i]);
      acc[i] = fmaf(zr[i].y, w1, acc[i]);
      acc[i] = fmaf(zr[i].z, w2, acc[i]);
      acc[i] = fmaf(zr[i].w, w3, acc[i]);
    }
  }
  #pragma unroll
  for (int i = 0; i < 4; ++i)
    zc[(long)(r0 + rl + 8 * i) * CD + c] = acc[i];
}

// ---------------- partial argmin over code chunk (double-buffered prefetch) --------
// block handles 512 points x 512 codes; thread = 2 points (p0, p0+256)
__global__ void k_argmin(const float* __restrict__ zc,
                         const float* __restrict__ cb,
                         const float* __restrict__ cnorm,
                         float* __restrict__ pd,
                         int* __restrict__ pi) {
  const int t  = threadIdx.x;
  const int pb = blockIdx.x & (PB - 1);
  const int cs = blockIdx.x >> 5;           // grid 512
  const int p0 = pb * PPB + t;
  const int p1 = p0 + 256;
  float z0[CD], z1[CD];
  const float4* a = (const float4*)(zc + (long)p0 * CD);
  const float4* b = (const float4*)(zc + (long)p1 * CD);
  #pragma unroll
  for (int q = 0; q < 8; ++q) {
    float4 va = a[q];
    z0[4 * q + 0] = va.x; z0[4 * q + 1] = va.y; z0[4 * q + 2] = va.z; z0[4 * q + 3] = va.w;
    float4 vb = b[q];
    z1[4 * q + 0] = vb.x; z1[4 * q + 1] = vb.y; z1[4 * q + 2] = vb.z; z1[4 * q + 3] = vb.w;
  }
  const int j0   = cs * CHUNK;
  const int jend = j0 + CHUNK;
  float bd0 = 1e30f, bd1 = 1e30f;
  int bj0 = j0, bj1 = j0;

  float4 bufA[8], bufB[8];
  float cnA, cnB;
  {
    const float4* c4 = (const float4*)(cb + (long)j0 * CD);
    #pragma unroll
    for (int q = 0; q < 8; ++q) bufA[q] = c4[q];
    cnA = cnorm[j0];
  }

  auto compute = [&](const float4* buf, float cn, int jj) {
    float s0a = 0.f, s0b = 0.f, s1a = 0.f, s1b = 0.f;
    #pragma unroll
    for (int q = 0; q < 8; ++q) {
      float4 c = buf[q];
      s0a = fmaf(z0[4 * q + 0], c.x, s0a);
      s1a = fmaf(z1[4 * q + 0], c.x, s1a);
      s0b = fmaf(z0[4 * q + 1], c.y, s0b);
      s1b = fmaf(z1[4 * q + 1], c.y, s1b);
      s0a = fmaf(z0[4 * q + 2], c.z, s0a);
      s1a = fmaf(z1[4 * q + 2], c.z, s1a);
      s0b = fmaf(z0[4 * q + 3], c.w, s0b);
      s1b = fmaf(z1[4 * q + 3], c.w, s1b);
    }
    const float d0 = fmaf(-2.f, s0a + s0b, cn);
    const float d1 = fmaf(-2.f, s1a + s1b, cn);
    if (d0 < bd0) { bd0 = d0; bj0 = jj; }
    if (d1 < bd1) { bd1 = d1; bj1 = jj; }
  };

  for (int j = j0; j < jend; j += 2) {
    {  // prefetch j+1 -> B
      const float4* n4 = (const float4*)(cb + (long)(j + 1) * CD);
      #pragma unroll
      for (int q = 0; q < 8; ++q) bufB[q] = n4[q];
      cnB = cnorm[j + 1];
    }
    compute(bufA, cnA, j);
    {  // prefetch j+2 -> A (clamped)
      const int jn = (j + 2 < jend) ? j + 2 : j0;
      const float4* n4 = (const float4*)(cb + (long)jn * CD);
      #pragma unroll
      for (int q = 0; q < 8; ++q) bufA[q] = n4[q];
      cnA = cnorm[jn];
    }
    compute(bufB, cnB, j + 1);
  }
  pd[cs * M + p0] = bd0;
  pd[cs * M + p1] = bd1;
  pi[cs * M + p0] = bj0;
  pi[cs * M + p1] = bj1;
}

// ---------------- combine partial argmins, gather z_q, loss partials ----------------
__global__ void k_combine(const float* __restrict__ zc,
                          const float* __restrict__ cb,
                          const float* __restrict__ pd,
                          const int* __restrict__ pi,
                          float* __restrict__ zq,
                          float* __restrict__ lpart) {
  const int t = threadIdx.x;
  const int p = blockIdx.x * 256 + t;   // grid 64
  float bd = 1e30f;
  int bj = 0;
  for (int s = 0; s < S; ++s) {
    float d = pd[s * M + p];
    int   i = pi[s * M + p];
    if (d < bd) { bd = d; bj = i; }
  }
  const float4* c4 = (const float4*)(cb + (long)bj * CD);
  const float4* z4 = (const float4*)(zc + (long)p * CD);
  float4* q4 = (float4*)(zq + (long)p * CD);
  float ls = 0.f;
  #pragma unroll
  for (int q = 0; q < 8; ++q) {
    float4 c = c4[q];
    float4 zz = z4[q];
    q4[q] = c;
    float dx = c.x - zz.x, dy = c.y - zz.y, dz = c.z - zz.z, dw = c.w - zz.w;
    ls += dx * dx + dy * dy + dz * dz + dw * dw;
  }
  #pragma unroll
  for (int m = 32; m >= 1; m >>= 1) ls += __shfl_xor(ls, m, 64);
  __shared__ float red[4];
  if ((t & 63) == 0) red[t >> 6] = ls;
  __syncthreads();
  if (t == 0) lpart[blockIdx.x] = red[0] + red[1] + red[2] + red[3];
}

__global__ void k_loss(const float* __restrict__ lpart, float* __restrict__ out_loss) {
  float v = (threadIdx.x < 64) ? lpart[threadIdx.x] : 0.f;
  #pragma unroll
  for (int m = 32; m >= 1; m >>= 1) v += __shfl_xor(v, m, 64);
  if (threadIdx.x == 0) *out_loss = 3.0f * v / (float)(M * CD);
}

// ---------------- out = z_q @ W_expand + b_expand ----------------
// block = 16 rows x 768 cols (3 groups of 256); thread holds ONE W column (32 regs)
__global__ void k_expand(const float* __restrict__ zq,
                         const float* __restrict__ We,
                         const float* __restrict__ be,
                         float* __restrict__ out) {
  const int t  = threadIdx.x;
  const int r0 = blockIdx.x * 16;   // grid 1024
  #pragma unroll
  for (int g = 0; g < 3; ++g) {
    const int c = g * 256 + t;
    float w[CD];
    #pragma unroll
    for (int k = 0; k < CD; ++k) w[k] = We[k * CIN + c];
    const float bb = be[c];
    for (int r = r0; r < r0 + 16; ++r) {
      const float4* q4 = (const float4*)(zq + (long)r * CD);
      float acc = bb;
      #pragma unroll
      for (int k4 = 0; k4 < 8; ++k4) {
        float4 qv = q4[k4];
        acc = fmaf(qv.x, w[4 * k4 + 0], acc);
        acc = fmaf(qv.y, w[4 * k4 + 1], acc);
        acc = fmaf(qv.z, w[4 * k4 + 2], acc);
        acc = fmaf(qv.w, w[4 * k4 + 3], acc);
      }
      out[(long)r * CIN + c] = acc;
    }
  }
}

extern "C" void kernel_launch(void* const* d_in, const int* in_sizes, int n_in,
                              void* d_out, int out_size, void* d_ws, size_t ws_size,
                              hipStream_t stream) {
  const float* z   = (const float*)d_in[0];
  const float* emb = (const float*)d_in[1];
  const float* Wc  = (const float*)d_in[2];
  const float* bc  = (const float*)d_in[3];
  const float* Wct = (const float*)d_in[4];
  const float* bct = (const float*)d_in[5];
  const float* We  = (const float*)d_in[6];
  const float* be  = (const float*)d_in[7];
  float* out = (float*)d_out;

  float* cb    = (float*)d_ws;          // NE*CD    = 262144
  float* cnorm = cb + NE * CD;          // NE       = 8192
  float* zc    = cnorm + NE;            // M*CD     = 524288
  float* pd    = zc + M * CD;           // S*M      = 262144
  float* zq    = pd + S * M;            // M*CD     = 524288
  float* lpart = zq + M * CD;           // 64
  int*   pi    = (int*)(lpart + 64);    // S*M      = 262144

  k_codebook<<<NE * CD / 256, 256, 0, stream>>>(emb, Wct, bct, cb, cnorm);
  k_compress<<<M / 32, 256, 0, stream>>>(z, Wc, bc, zc);
  k_argmin<<<PB * S, 256, 0, stream>>>(zc, cb, cnorm, pd, pi);
  k_combine<<<M / 256, 256, 0, stream>>>(zc, cb, pd, pi, zq, lpart);
  k_loss<<<1, 64, 0, stream>>>(lpart, out + (long)M * CIN);
  k_expand<<<M / 32 * 2, 256, 0, stream>>>(zq, We, be, out);
}

// Round 3
// 343.447 us; speedup vs baseline: 1.7763x; 1.3039x over previous
//
#include <hip/hip_runtime.h>

constexpr int CIN = 768;
constexpr int CD  = 32;
constexpr int NE  = 8192;
constexpr int M   = 16384;      // B*N = 64*256
constexpr int S   = 64;         // code-chunk splits for argmin (8 blocks/CU)
constexpr int CHUNK = NE / S;   // 128 codes per chunk
constexpr int PB  = 32;         // point-blocks for argmin
constexpr int PPB = M / PB;     // 512 points per block

// ---------------- codebook = emb @ W_ct + b_ct ; cnorm = ||row||^2 ----------------
__global__ void k_codebook(const float* __restrict__ emb,
                           const float* __restrict__ Wct,
                           const float* __restrict__ bct,
                           float* __restrict__ cb,
                           float* __restrict__ cnorm) {
  __shared__ float w[CD * CD];
  const int t = threadIdx.x;
  for (int i = t; i < CD * CD; i += 256) w[i] = Wct[i];
  __syncthreads();
  const int g   = blockIdx.x * 256 + t;   // grid 1024 -> 262144 elems
  const int row = g >> 5;
  const int col = g & 31;
  float acc = bct[col];
  const float* er = emb + row * CD;
  #pragma unroll
  for (int k = 0; k < CD; ++k) acc = fmaf(er[k], w[k * CD + col], acc);
  cb[g] = acc;
  float v = acc * acc;
  #pragma unroll
  for (int m = 16; m >= 1; m >>= 1) v += __shfl_xor(v, m, 64);
  if (col == 0) cnorm[row] = v;
}

// ---------------- zc = z @ W_compress + b_compress ----------------
// block = 256 threads = 32 cols x 8 row-lanes; 2 rows/thread -> 16 rows/block
__global__ void k_compress(const float* __restrict__ z,
                           const float* __restrict__ Wc,
                           const float* __restrict__ bc,
                           float* __restrict__ zc) {
  const int t  = threadIdx.x;
  const int c  = t & 31;
  const int rl = t >> 5;                 // 0..7
  const int r0 = blockIdx.x * 16;        // grid 1024
  float acc[2];
  acc[0] = bc[c];
  acc[1] = acc[0];
  #pragma unroll 4
  for (int k4 = 0; k4 < CIN / 4; ++k4) {
    float4 zr0 = ((const float4*)(z + (long)(r0 + rl) * CIN))[k4];
    float4 zr1 = ((const float4*)(z + (long)(r0 + rl + 8) * CIN))[k4];
    const float w0 = Wc[(k4 * 4 + 0) * CD + c];
    const float w1 = Wc[(k4 * 4 + 1) * CD + c];
    const float w2 = Wc[(k4 * 4 + 2) * CD + c];
    const float w3 = Wc[(k4 * 4 + 3) * CD + c];
    acc[0] = fmaf(zr0.x, w0, acc[0]);
    acc[1] = fmaf(zr1.x, w0, acc[1]);
    acc[0] = fmaf(zr0.y, w1, acc[0]);
    acc[1] = fmaf(zr1.y, w1, acc[1]);
    acc[0] = fmaf(zr0.z, w2, acc[0]);
    acc[1] = fmaf(zr1.z, w2, acc[1]);
    acc[0] = fmaf(zr0.w, w3, acc[0]);
    acc[1] = fmaf(zr1.w, w3, acc[1]);
  }
  zc[(long)(r0 + rl) * CD + c]     = acc[0];
  zc[(long)(r0 + rl + 8) * CD + c] = acc[1];
}

// ---------------- partial argmin over code chunk (double-buffered prefetch) --------
// block handles 512 points x 128 codes; thread = 2 points (p0, p0+256)
__global__ void k_argmin(const float* __restrict__ zc,
                         const float* __restrict__ cb,
                         const float* __restrict__ cnorm,
                         float* __restrict__ pd,
                         int* __restrict__ pi) {
  const int t  = threadIdx.x;
  const int pb = blockIdx.x & (PB - 1);
  const int cs = blockIdx.x >> 5;           // grid PB*S = 2048
  const int p0 = pb * PPB + t;
  const int p1 = p0 + 256;
  float z0[CD], z1[CD];
  const float4* a = (const float4*)(zc + (long)p0 * CD);
  const float4* b = (const float4*)(zc + (long)p1 * CD);
  #pragma unroll
  for (int q = 0; q < 8; ++q) {
    float4 va = a[q];
    z0[4 * q + 0] = va.x; z0[4 * q + 1] = va.y; z0[4 * q + 2] = va.z; z0[4 * q + 3] = va.w;
    float4 vb = b[q];
    z1[4 * q + 0] = vb.x; z1[4 * q + 1] = vb.y; z1[4 * q + 2] = vb.z; z1[4 * q + 3] = vb.w;
  }
  const int j0   = cs * CHUNK;
  const int jend = j0 + CHUNK;
  float bd0 = 1e30f, bd1 = 1e30f;
  int bj0 = j0, bj1 = j0;

  float4 bufA[8], bufB[8];
  float cnA, cnB;
  {
    const float4* c4 = (const float4*)(cb + (long)j0 * CD);
    #pragma unroll
    for (int q = 0; q < 8; ++q) bufA[q] = c4[q];
    cnA = cnorm[j0];
  }

  auto compute = [&](const float4* buf, float cn, int jj) {
    float s0a = 0.f, s0b = 0.f, s1a = 0.f, s1b = 0.f;
    #pragma unroll
    for (int q = 0; q < 8; ++q) {
      float4 c = buf[q];
      s0a = fmaf(z0[4 * q + 0], c.x, s0a);
      s1a = fmaf(z1[4 * q + 0], c.x, s1a);
      s0b = fmaf(z0[4 * q + 1], c.y, s0b);
      s1b = fmaf(z1[4 * q + 1], c.y, s1b);
      s0a = fmaf(z0[4 * q + 2], c.z, s0a);
      s1a = fmaf(z1[4 * q + 2], c.z, s1a);
      s0b = fmaf(z0[4 * q + 3], c.w, s0b);
      s1b = fmaf(z1[4 * q + 3], c.w, s1b);
    }
    const float d0 = fmaf(-2.f, s0a + s0b, cn);
    const float d1 = fmaf(-2.f, s1a + s1b, cn);
    if (d0 < bd0) { bd0 = d0; bj0 = jj; }
    if (d1 < bd1) { bd1 = d1; bj1 = jj; }
  };

  for (int j = j0; j < jend; j += 2) {
    {  // prefetch j+1 -> B
      const float4* n4 = (const float4*)(cb + (long)(j + 1) * CD);
      #pragma unroll
      for (int q = 0; q < 8; ++q) bufB[q] = n4[q];
      cnB = cnorm[j + 1];
    }
    compute(bufA, cnA, j);
    {  // prefetch j+2 -> A (clamped)
      const int jn = (j + 2 < jend) ? j + 2 : j0;
      const float4* n4 = (const float4*)(cb + (long)jn * CD);
      #pragma unroll
      for (int q = 0; q < 8; ++q) bufA[q] = n4[q];
      cnA = cnorm[jn];
    }
    compute(bufB, cnB, j + 1);
  }
  pd[cs * M + p0] = bd0;
  pd[cs * M + p1] = bd1;
  pi[cs * M + p0] = bj0;
  pi[cs * M + p1] = bj1;
}

// ---------------- combine partial argmins, gather z_q, loss partials ----------------
__global__ void k_combine(const float* __restrict__ zc,
                          const float* __restrict__ cb,
                          const float* __restrict__ pd,
                          const int* __restrict__ pi,
                          float* __restrict__ zq,
                          float* __restrict__ lpart) {
  const int t = threadIdx.x;
  const int p = blockIdx.x * 128 + t;   // grid 128, block 128
  float bd = 1e30f;
  int bj = 0;
  for (int s = 0; s < S; ++s) {
    float d = pd[s * M + p];
    int   i = pi[s * M + p];
    if (d < bd) { bd = d; bj = i; }
  }
  const float4* c4 = (const float4*)(cb + (long)bj * CD);
  const float4* z4 = (const float4*)(zc + (long)p * CD);
  float4* q4 = (float4*)(zq + (long)p * CD);
  float ls = 0.f;
  #pragma unroll
  for (int q = 0; q < 8; ++q) {
    float4 c = c4[q];
    float4 zz = z4[q];
    q4[q] = c;
    float dx = c.x - zz.x, dy = c.y - zz.y, dz = c.z - zz.z, dw = c.w - zz.w;
    ls += dx * dx + dy * dy + dz * dz + dw * dw;
  }
  #pragma unroll
  for (int m = 32; m >= 1; m >>= 1) ls += __shfl_xor(ls, m, 64);
  __shared__ float red[2];
  if ((t & 63) == 0) red[t >> 6] = ls;
  __syncthreads();
  if (t == 0) lpart[blockIdx.x] = red[0] + red[1];
}

__global__ void k_loss(const float* __restrict__ lpart, float* __restrict__ out_loss) {
  float v = lpart[threadIdx.x] + lpart[threadIdx.x + 64];
  #pragma unroll
  for (int m = 32; m >= 1; m >>= 1) v += __shfl_xor(v, m, 64);
  if (threadIdx.x == 0) *out_loss = 3.0f * v / (float)(M * CD);
}

// ---------------- out = z_q @ W_expand + b_expand ----------------
// block = 16 rows x 256 cols (one col-group); thread holds ONE W column (32 regs)
__global__ void k_expand(const float* __restrict__ zq,
                         const float* __restrict__ We,
                         const float* __restrict__ be,
                         float* __restrict__ out) {
  const int t  = threadIdx.x;
  const int rb = blockIdx.x & 1023;        // grid 3*1024
  const int g  = blockIdx.x >> 10;         // 0..2
  const int c  = g * 256 + t;
  const int r0 = rb * 16;
  float w[CD];
  #pragma unroll
  for (int k = 0; k < CD; ++k) w[k] = We[k * CIN + c];
  const float bb = be[c];
  for (int r = r0; r < r0 + 16; ++r) {
    const float4* q4 = (const float4*)(zq + (long)r * CD);
    float acc = bb;
    #pragma unroll
    for (int k4 = 0; k4 < 8; ++k4) {
      float4 qv = q4[k4];
      acc = fmaf(qv.x, w[4 * k4 + 0], acc);
      acc = fmaf(qv.y, w[4 * k4 + 1], acc);
      acc = fmaf(qv.z, w[4 * k4 + 2], acc);
      acc = fmaf(qv.w, w[4 * k4 + 3], acc);
    }
    out[(long)r * CIN + c] = acc;
  }
}

extern "C" void kernel_launch(void* const* d_in, const int* in_sizes, int n_in,
                              void* d_out, int out_size, void* d_ws, size_t ws_size,
                              hipStream_t stream) {
  const float* z   = (const float*)d_in[0];
  const float* emb = (const float*)d_in[1];
  const float* Wc  = (const float*)d_in[2];
  const float* bc  = (const float*)d_in[3];
  const float* Wct = (const float*)d_in[4];
  const float* bct = (const float*)d_in[5];
  const float* We  = (const float*)d_in[6];
  const float* be  = (const float*)d_in[7];
  float* out = (float*)d_out;

  float* cb    = (float*)d_ws;          // NE*CD    = 262144
  float* cnorm = cb + NE * CD;          // NE       = 8192
  float* zc    = cnorm + NE;            // M*CD     = 524288
  float* pd    = zc + M * CD;           // S*M      = 1048576
  float* zq    = pd + S * M;            // M*CD     = 524288
  float* lpart = zq + M * CD;           // 128
  int*   pi    = (int*)(lpart + 128);   // S*M      = 1048576

  k_codebook<<<NE * CD / 256, 256, 0, stream>>>(emb, Wct, bct, cb, cnorm);
  k_compress<<<M / 16, 256, 0, stream>>>(z, Wc, bc, zc);
  k_argmin<<<PB * S, 256, 0, stream>>>(zc, cb, cnorm, pd, pi);
  k_combine<<<M / 128, 128, 0, stream>>>(zc, cb, pd, pi, zq, lpart);
  k_loss<<<1, 64, 0, stream>>>(lpart, out + (long)M * CIN);
  k_expand<<<3 * 1024, 256, 0, stream>>>(zq, We, be, out);
}

// Round 4
// 306.837 us; speedup vs baseline: 1.9883x; 1.1193x over previous
//
#include <hip/hip_runtime.h>

constexpr int CIN = 768;
constexpr int CD  = 32;
constexpr int NE  = 8192;
constexpr int M   = 16384;      // B*N = 64*256
constexpr int SCH = 64;         // code chunks for argmin
constexpr int CPC = NE / SCH;   // 128 codes per chunk
constexpr int PTB = 128;        // points per argmin block (4 waves x 32)
#define MARGIN 0.05f

typedef short short8 __attribute__((ext_vector_type(8)));
typedef float f32x4  __attribute__((ext_vector_type(4)));

// RNE split of fp32 into bf16 hi + bf16 lo-residual
__device__ inline void split_bf16(float x, unsigned short& h, unsigned short& l) {
  unsigned u = __float_as_uint(x);
  unsigned hb = (u + 0x7FFFu + ((u >> 16) & 1u)) >> 16;
  float hf = __uint_as_float(hb << 16);
  float r = x - hf;
  unsigned u2 = __float_as_uint(r);
  unsigned lb = (u2 + 0x7FFFu + ((u2 >> 16) & 1u)) >> 16;
  h = (unsigned short)hb;
  l = (unsigned short)lb;
}

// ---------------- codebook = emb @ W_ct + b_ct ; cnorm; bf16 split ----------------
__global__ void k_codebook(const float* __restrict__ emb,
                           const float* __restrict__ Wct,
                           const float* __restrict__ bct,
                           float* __restrict__ cb,
                           float* __restrict__ cnorm,
                           unsigned short* __restrict__ ch,
                           unsigned short* __restrict__ cl) {
  __shared__ float w[CD * CD];
  const int t = threadIdx.x;
  for (int i = t; i < CD * CD; i += 256) w[i] = Wct[i];
  __syncthreads();
  const int g   = blockIdx.x * 256 + t;   // grid 1024
  const int row = g >> 5;
  const int col = g & 31;
  float acc = bct[col];
  const float* er = emb + row * CD;
  #pragma unroll
  for (int k = 0; k < CD; ++k) acc = fmaf(er[k], w[k * CD + col], acc);
  cb[g] = acc;
  unsigned short h, l;
  split_bf16(acc, h, l);
  ch[g] = h; cl[g] = l;
  float v = acc * acc;
  #pragma unroll
  for (int m = 16; m >= 1; m >>= 1) v += __shfl_xor(v, m, 64);
  if (col == 0) cnorm[row] = v;
}

// ---------------- zc = z @ W_compress + b ; bf16 split ----------------
__global__ void k_compress(const float* __restrict__ z,
                           const float* __restrict__ Wc,
                           const float* __restrict__ bc,
                           float* __restrict__ zc,
                           unsigned short* __restrict__ zh,
                           unsigned short* __restrict__ zl) {
  const int t  = threadIdx.x;
  const int c  = t & 31;
  const int rl = t >> 5;                 // 0..7
  const int r0 = blockIdx.x * 16;        // grid 1024
  float acc[2];
  acc[0] = bc[c];
  acc[1] = acc[0];
  #pragma unroll 4
  for (int k4 = 0; k4 < CIN / 4; ++k4) {
    float4 zr0 = ((const float4*)(z + (long)(r0 + rl) * CIN))[k4];
    float4 zr1 = ((const float4*)(z + (long)(r0 + rl + 8) * CIN))[k4];
    const float w0 = Wc[(k4 * 4 + 0) * CD + c];
    const float w1 = Wc[(k4 * 4 + 1) * CD + c];
    const float w2 = Wc[(k4 * 4 + 2) * CD + c];
    const float w3 = Wc[(k4 * 4 + 3) * CD + c];
    acc[0] = fmaf(zr0.x, w0, acc[0]);
    acc[1] = fmaf(zr1.x, w0, acc[1]);
    acc[0] = fmaf(zr0.y, w1, acc[0]);
    acc[1] = fmaf(zr1.y, w1, acc[1]);
    acc[0] = fmaf(zr0.z, w2, acc[0]);
    acc[1] = fmaf(zr1.z, w2, acc[1]);
    acc[0] = fmaf(zr0.w, w3, acc[0]);
    acc[1] = fmaf(zr1.w, w3, acc[1]);
  }
  #pragma unroll
  for (int i = 0; i < 2; ++i) {
    const long idx = (long)(r0 + rl + 8 * i) * CD + c;
    zc[idx] = acc[i];
    unsigned short h, l;
    split_bf16(acc[i], h, l);
    zh[idx] = h; zl[idx] = l;
  }
}

// ---------------- MFMA approx distances + per-chunk argmin ----------------
// grid = (M/PTB=128) x SCH=64 -> 8192 blocks; wave handles 32 points x 128 codes
__global__ __launch_bounds__(256) void k_argmin(
    const unsigned short* __restrict__ zh, const unsigned short* __restrict__ zl,
    const unsigned short* __restrict__ ch, const unsigned short* __restrict__ cl,
    const float* __restrict__ cnorm,
    float* __restrict__ pd, int* __restrict__ pi) {
  const int pb   = blockIdx.x & (M / PTB - 1);   // 0..127
  const int cid  = blockIdx.x >> 7;              // 0..63
  const int lane = threadIdx.x & 63;
  const int wv   = threadIdx.x >> 6;
  const int col  = lane & 15;
  const int quad = lane >> 4;
  const int p0   = pb * PTB + wv * 32;

  const short8 Ah0 = *(const short8*)(zh + (long)(p0 + col) * CD + quad * 8);
  const short8 Al0 = *(const short8*)(zl + (long)(p0 + col) * CD + quad * 8);
  const short8 Ah1 = *(const short8*)(zh + (long)(p0 + 16 + col) * CD + quad * 8);
  const short8 Al1 = *(const short8*)(zl + (long)(p0 + 16 + col) * CD + quad * 8);

  const int jb = cid * CPC;
  float bd0[4], bd1[4];
  int   bj0[4], bj1[4];
  #pragma unroll
  for (int r = 0; r < 4; ++r) { bd0[r] = 1e30f; bd1[r] = 1e30f; bj0[r] = 0; bj1[r] = 0; }

  for (int t = 0; t < CPC / 16; ++t) {           // 8 tiles of 16 codes
    const int cb0 = jb + t * 16;
    const short8 Bh = *(const short8*)(ch + (long)(cb0 + col) * CD + quad * 8);
    const short8 Bl = *(const short8*)(cl + (long)(cb0 + col) * CD + quad * 8);
    f32x4 g0 = {0.f, 0.f, 0.f, 0.f};
    f32x4 g1 = {0.f, 0.f, 0.f, 0.f};
    g0 = __builtin_amdgcn_mfma_f32_16x16x32_bf16(Ah0, Bh, g0, 0, 0, 0);
    g0 = __builtin_amdgcn_mfma_f32_16x16x32_bf16(Ah0, Bl, g0, 0, 0, 0);
    g0 = __builtin_amdgcn_mfma_f32_16x16x32_bf16(Al0, Bh, g0, 0, 0, 0);
    g1 = __builtin_amdgcn_mfma_f32_16x16x32_bf16(Ah1, Bh, g1, 0, 0, 0);
    g1 = __builtin_amdgcn_mfma_f32_16x16x32_bf16(Ah1, Bl, g1, 0, 0, 0);
    g1 = __builtin_amdgcn_mfma_f32_16x16x32_bf16(Al1, Bh, g1, 0, 0, 0);
    const float cnv = cnorm[cb0 + col];
    #pragma unroll
    for (int r = 0; r < 4; ++r) {
      const float d0 = fmaf(-2.f, g0[r], cnv);
      if (d0 < bd0[r]) { bd0[r] = d0; bj0[r] = t; }
      const float d1 = fmaf(-2.f, g1[r], cnv);
      if (d1 < bd1[r]) { bd1[r] = d1; bj1[r] = t; }
    }
  }

  // local code index within chunk
  int jl0[4], jl1[4];
  #pragma unroll
  for (int r = 0; r < 4; ++r) { jl0[r] = bj0[r] * 16 + col; jl1[r] = bj1[r] * 16 + col; }
  // reduce across the 16 lanes (cols) sharing each row
  #pragma unroll
  for (int mm = 1; mm <= 8; mm <<= 1) {
    #pragma unroll
    for (int r = 0; r < 4; ++r) {
      float od = __shfl_xor(bd0[r], mm, 64); int oj = __shfl_xor(jl0[r], mm, 64);
      if (od < bd0[r] || (od == bd0[r] && oj < jl0[r])) { bd0[r] = od; jl0[r] = oj; }
      od = __shfl_xor(bd1[r], mm, 64); oj = __shfl_xor(jl1[r], mm, 64);
      if (od < bd1[r] || (od == bd1[r] && oj < jl1[r])) { bd1[r] = od; jl1[r] = oj; }
    }
  }
  if (col == 0) {
    #pragma unroll
    for (int r = 0; r < 4; ++r) {
      const int pA = p0 + quad * 4 + r;
      pd[(long)pA * SCH + cid] = bd0[r];
      pi[(long)pA * SCH + cid] = jb + jl0[r];
      const int pB = pA + 16;
      pd[(long)pB * SCH + cid] = bd1[r];
      pi[(long)pB * SCH + cid] = jb + jl1[r];
    }
  }
}

// ---------------- exact-fp32 rescue + argmin finalize + zq gather + loss ----------------
// one wave per point; grid 4096 x 256
__global__ __launch_bounds__(256) void k_rescue(
    const float* __restrict__ zc, const float* __restrict__ cb,
    const float* __restrict__ cnorm,
    const float* __restrict__ pd, const int* __restrict__ pi,
    float* __restrict__ zq, float* __restrict__ lpart) {
  const int lane = threadIdx.x & 63;
  const int wv   = threadIdx.x >> 6;
  const int p    = blockIdx.x * 4 + wv;

  const float m = pd[(long)p * SCH + lane];
  float dstar = m;
  #pragma unroll
  for (int mm = 1; mm <= 32; mm <<= 1) dstar = fminf(dstar, __shfl_xor(dstar, mm, 64));
  unsigned long long mask = __ballot(m <= dstar + MARGIN);

  float zr[CD];
  {
    const float4* z4 = (const float4*)(zc + (long)p * CD);
    #pragma unroll
    for (int q = 0; q < 8; ++q) {
      float4 v = z4[q];
      zr[4 * q + 0] = v.x; zr[4 * q + 1] = v.y; zr[4 * q + 2] = v.z; zr[4 * q + 3] = v.w;
    }
  }

  float bd = 1e30f;
  int   bj = 0x7fffffff;
  while (mask) {
    const int c = (int)__builtin_ctzll(mask);
    mask &= mask - 1;
    #pragma unroll
    for (int u = 0; u < 2; ++u) {
      const int j = c * CPC + u * 64 + lane;
      const float4* crow = (const float4*)(cb + (long)j * CD);
      float acc = 0.f;
      #pragma unroll
      for (int q = 0; q < 8; ++q) {
        float4 cv = crow[q];
        acc = fmaf(zr[4 * q + 0], cv.x, acc);
        acc = fmaf(zr[4 * q + 1], cv.y, acc);
        acc = fmaf(zr[4 * q + 2], cv.z, acc);
        acc = fmaf(zr[4 * q + 3], cv.w, acc);
      }
      const float d = fmaf(-2.f, acc, cnorm[j]);
      if (d < bd) { bd = d; bj = j; }
    }
  }
  #pragma unroll
  for (int mm = 1; mm <= 32; mm <<= 1) {
    const float od = __shfl_xor(bd, mm, 64);
    const int   oj = __shfl_xor(bj, mm, 64);
    if (od < bd || (od == bd && oj < bj)) { bd = od; bj = oj; }
  }

  float ls = 0.f;
  if (lane < 32) {
    const float cv = cb[(long)bj * CD + lane];
    const float zv = zc[(long)p * CD + lane];
    zq[(long)p * CD + lane] = cv;
    const float df = cv - zv;
    ls = df * df;
  }
  #pragma unroll
  for (int mm = 1; mm <= 32; mm <<= 1) ls += __shfl_xor(ls, mm, 64);
  if (lane == 0) lpart[p] = ls;
}

__global__ void k_loss(const float* __restrict__ lpart, float* __restrict__ out_loss) {
  __shared__ float red[4];
  const int t = threadIdx.x;
  float v = 0.f;
  for (int k = t; k < M; k += 256) v += lpart[k];
  #pragma unroll
  for (int mm = 1; mm <= 32; mm <<= 1) v += __shfl_xor(v, mm, 64);
  if ((t & 63) == 0) red[t >> 6] = v;
  __syncthreads();
  if (t == 0) out_loss[0] = 3.0f * (red[0] + red[1] + red[2] + red[3]) / (float)(M * CD);
}

// ---------------- out = z_q @ W_expand + b_expand ----------------
__global__ void k_expand(const float* __restrict__ zq,
                         const float* __restrict__ We,
                         const float* __restrict__ be,
                         float* __restrict__ out) {
  const int t  = threadIdx.x;
  const int rb = blockIdx.x & 1023;        // grid 3*1024
  const int g  = blockIdx.x >> 10;         // 0..2
  const int c  = g * 256 + t;
  const int r0 = rb * 16;
  float w[CD];
  #pragma unroll
  for (int k = 0; k < CD; ++k) w[k] = We[k * CIN + c];
  const float bb = be[c];
  for (int r = r0; r < r0 + 16; ++r) {
    const float4* q4 = (const float4*)(zq + (long)r * CD);
    float acc = bb;
    #pragma unroll
    for (int k4 = 0; k4 < 8; ++k4) {
      float4 qv = q4[k4];
      acc = fmaf(qv.x, w[4 * k4 + 0], acc);
      acc = fmaf(qv.y, w[4 * k4 + 1], acc);
      acc = fmaf(qv.z, w[4 * k4 + 2], acc);
      acc = fmaf(qv.w, w[4 * k4 + 3], acc);
    }
    out[(long)r * CIN + c] = acc;
  }
}

extern "C" void kernel_launch(void* const* d_in, const int* in_sizes, int n_in,
                              void* d_out, int out_size, void* d_ws, size_t ws_size,
                              hipStream_t stream) {
  const float* z   = (const float*)d_in[0];
  const float* emb = (const float*)d_in[1];
  const float* Wc  = (const float*)d_in[2];
  const float* bc  = (const float*)d_in[3];
  const float* Wct = (const float*)d_in[4];
  const float* bct = (const float*)d_in[5];
  const float* We  = (const float*)d_in[6];
  const float* be  = (const float*)d_in[7];
  float* out = (float*)d_out;

  float* cb    = (float*)d_ws;              // NE*CD        = 262144 f
  float* cnorm = cb + NE * CD;              // NE           = 8192 f
  float* zc    = cnorm + NE;                // M*CD         = 524288 f
  float* zq    = zc + M * CD;               // M*CD         = 524288 f
  float* pd    = zq + M * CD;               // M*SCH        = 1048576 f
  float* lpart = pd + (long)M * SCH;        // M            = 16384 f
  int*   pi    = (int*)(lpart + M);         // M*SCH        = 1048576 i
  unsigned short* zh = (unsigned short*)(pi + (long)M * SCH);  // M*CD ushort
  unsigned short* zl = zh + M * CD;
  unsigned short* ch = zl + M * CD;         // NE*CD ushort
  unsigned short* cl = ch + NE * CD;

  k_codebook<<<NE * CD / 256, 256, 0, stream>>>(emb, Wct, bct, cb, cnorm, ch, cl);
  k_compress<<<M / 16, 256, 0, stream>>>(z, Wc, bc, zc, zh, zl);
  k_argmin<<<(M / PTB) * SCH, 256, 0, stream>>>(zh, zl, ch, cl, cnorm, pd, pi);
  k_rescue<<<M / 4, 256, 0, stream>>>(zc, cb, cnorm, pd, pi, zq, lpart);
  k_loss<<<1, 256, 0, stream>>>(lpart, out + (long)M * CIN);
  k_expand<<<3 * 1024, 256, 0, stream>>>(zq, We, be, out);
}

// Round 5
// 285.743 us; speedup vs baseline: 2.1351x; 1.0738x over previous
//
#include <hip/hip_runtime.h>

constexpr int CIN = 768;
constexpr int CD  = 32;
constexpr int NE  = 8192;
constexpr int M   = 16384;      // B*N = 64*256
constexpr int SCH = 64;         // code chunks for argmin
constexpr int CPC = NE / SCH;   // 128 codes per chunk
constexpr int PTB = 128;        // points per argmin block (4 waves x 32)
#define MARGIN 0.05f

typedef short short8 __attribute__((ext_vector_type(8)));
typedef float f32x4  __attribute__((ext_vector_type(4)));

// RNE split of fp32 into bf16 hi + bf16 lo-residual
__device__ inline void split_bf16(float x, unsigned short& h, unsigned short& l) {
  unsigned u = __float_as_uint(x);
  unsigned hb = (u + 0x7FFFu + ((u >> 16) & 1u)) >> 16;
  float hf = __uint_as_float(hb << 16);
  float r = x - hf;
  unsigned u2 = __float_as_uint(r);
  unsigned lb = (u2 + 0x7FFFu + ((u2 >> 16) & 1u)) >> 16;
  h = (unsigned short)hb;
  l = (unsigned short)lb;
}

// ---------------- codebook = emb @ W_ct + b_ct ; cnorm; bf16 split ----------------
__global__ void k_codebook(const float* __restrict__ emb,
                           const float* __restrict__ Wct,
                           const float* __restrict__ bct,
                           float* __restrict__ cb,
                           float* __restrict__ cnorm,
                           unsigned short* __restrict__ ch,
                           unsigned short* __restrict__ cl) {
  __shared__ float w[CD * CD];
  const int t = threadIdx.x;
  for (int i = t; i < CD * CD; i += 256) w[i] = Wct[i];
  __syncthreads();
  const int g   = blockIdx.x * 256 + t;   // grid 1024
  const int row = g >> 5;
  const int col = g & 31;
  float acc = bct[col];
  const float* er = emb + row * CD;
  #pragma unroll
  for (int k = 0; k < CD; ++k) acc = fmaf(er[k], w[k * CD + col], acc);
  cb[g] = acc;
  unsigned short h, l;
  split_bf16(acc, h, l);
  ch[g] = h; cl[g] = l;
  float v = acc * acc;
  #pragma unroll
  for (int m = 16; m >= 1; m >>= 1) v += __shfl_xor(v, m, 64);
  if (col == 0) cnorm[row] = v;
}

// ---------------- zc = z @ W_compress + b ; bf16 split ----------------
// thread = 1 row x 4 cols; block = 32 rows; grid 512
__global__ __launch_bounds__(256) void k_compress(
    const float* __restrict__ z,
    const float* __restrict__ Wc,
    const float* __restrict__ bc,
    float* __restrict__ zc,
    unsigned short* __restrict__ zh,
    unsigned short* __restrict__ zl) {
  const int t   = threadIdx.x;
  const int c0  = (t & 7) * 4;
  const int row = blockIdx.x * 32 + (t >> 3);
  const float4* zr = (const float4*)(z + (long)row * CIN);
  float4 acc = *(const float4*)(bc + c0);
  #pragma unroll 8
  for (int k4 = 0; k4 < CIN / 4; ++k4) {
    const float4 zv = zr[k4];
    const float4 w0 = *(const float4*)(Wc + (k4 * 4 + 0) * CD + c0);
    const float4 w1 = *(const float4*)(Wc + (k4 * 4 + 1) * CD + c0);
    const float4 w2 = *(const float4*)(Wc + (k4 * 4 + 2) * CD + c0);
    const float4 w3 = *(const float4*)(Wc + (k4 * 4 + 3) * CD + c0);
    acc.x = fmaf(zv.x, w0.x, acc.x);
    acc.y = fmaf(zv.x, w0.y, acc.y);
    acc.z = fmaf(zv.x, w0.z, acc.z);
    acc.w = fmaf(zv.x, w0.w, acc.w);
    acc.x = fmaf(zv.y, w1.x, acc.x);
    acc.y = fmaf(zv.y, w1.y, acc.y);
    acc.z = fmaf(zv.y, w1.z, acc.z);
    acc.w = fmaf(zv.y, w1.w, acc.w);
    acc.x = fmaf(zv.z, w2.x, acc.x);
    acc.y = fmaf(zv.z, w2.y, acc.y);
    acc.z = fmaf(zv.z, w2.z, acc.z);
    acc.w = fmaf(zv.z, w2.w, acc.w);
    acc.x = fmaf(zv.w, w3.x, acc.x);
    acc.y = fmaf(zv.w, w3.y, acc.y);
    acc.z = fmaf(zv.w, w3.z, acc.z);
    acc.w = fmaf(zv.w, w3.w, acc.w);
  }
  const long idx = (long)row * CD + c0;
  *(float4*)(zc + idx) = acc;
  ushort4 h4, l4;
  split_bf16(acc.x, h4.x, l4.x);
  split_bf16(acc.y, h4.y, l4.y);
  split_bf16(acc.z, h4.z, l4.z);
  split_bf16(acc.w, h4.w, l4.w);
  *(ushort4*)(zh + idx) = h4;
  *(ushort4*)(zl + idx) = l4;
}

// ---------------- MFMA approx distances + per-chunk argmin ----------------
// grid = (M/PTB=128) x SCH=64 -> 8192 blocks; wave handles 32 points x 128 codes
__global__ __launch_bounds__(256) void k_argmin(
    const unsigned short* __restrict__ zh, const unsigned short* __restrict__ zl,
    const unsigned short* __restrict__ ch, const unsigned short* __restrict__ cl,
    const float* __restrict__ cnorm,
    float* __restrict__ pd, int* __restrict__ pi) {
  const int pb   = blockIdx.x & (M / PTB - 1);   // 0..127
  const int cid  = blockIdx.x >> 7;              // 0..63
  const int lane = threadIdx.x & 63;
  const int wv   = threadIdx.x >> 6;
  const int col  = lane & 15;
  const int quad = lane >> 4;
  const int p0   = pb * PTB + wv * 32;

  const short8 Ah0 = *(const short8*)(zh + (long)(p0 + col) * CD + quad * 8);
  const short8 Al0 = *(const short8*)(zl + (long)(p0 + col) * CD + quad * 8);
  const short8 Ah1 = *(const short8*)(zh + (long)(p0 + 16 + col) * CD + quad * 8);
  const short8 Al1 = *(const short8*)(zl + (long)(p0 + 16 + col) * CD + quad * 8);

  const int jb = cid * CPC;
  float bd0[4], bd1[4];
  int   bj0[4], bj1[4];
  #pragma unroll
  for (int r = 0; r < 4; ++r) { bd0[r] = 1e30f; bd1[r] = 1e30f; bj0[r] = 0; bj1[r] = 0; }

  for (int t = 0; t < CPC / 16; ++t) {           // 8 tiles of 16 codes
    const int cb0 = jb + t * 16;
    const short8 Bh = *(const short8*)(ch + (long)(cb0 + col) * CD + quad * 8);
    const short8 Bl = *(const short8*)(cl + (long)(cb0 + col) * CD + quad * 8);
    f32x4 g0 = {0.f, 0.f, 0.f, 0.f};
    f32x4 g1 = {0.f, 0.f, 0.f, 0.f};
    g0 = __builtin_amdgcn_mfma_f32_16x16x32_bf16(Ah0, Bh, g0, 0, 0, 0);
    g0 = __builtin_amdgcn_mfma_f32_16x16x32_bf16(Ah0, Bl, g0, 0, 0, 0);
    g0 = __builtin_amdgcn_mfma_f32_16x16x32_bf16(Al0, Bh, g0, 0, 0, 0);
    g1 = __builtin_amdgcn_mfma_f32_16x16x32_bf16(Ah1, Bh, g1, 0, 0, 0);
    g1 = __builtin_amdgcn_mfma_f32_16x16x32_bf16(Ah1, Bl, g1, 0, 0, 0);
    g1 = __builtin_amdgcn_mfma_f32_16x16x32_bf16(Al1, Bh, g1, 0, 0, 0);
    const float cnv = cnorm[cb0 + col];
    #pragma unroll
    for (int r = 0; r < 4; ++r) {
      const float d0 = fmaf(-2.f, g0[r], cnv);
      if (d0 < bd0[r]) { bd0[r] = d0; bj0[r] = t; }
      const float d1 = fmaf(-2.f, g1[r], cnv);
      if (d1 < bd1[r]) { bd1[r] = d1; bj1[r] = t; }
    }
  }

  int jl0[4], jl1[4];
  #pragma unroll
  for (int r = 0; r < 4; ++r) { jl0[r] = bj0[r] * 16 + col; jl1[r] = bj1[r] * 16 + col; }
  #pragma unroll
  for (int mm = 1; mm <= 8; mm <<= 1) {
    #pragma unroll
    for (int r = 0; r < 4; ++r) {
      float od = __shfl_xor(bd0[r], mm, 64); int oj = __shfl_xor(jl0[r], mm, 64);
      if (od < bd0[r] || (od == bd0[r] && oj < jl0[r])) { bd0[r] = od; jl0[r] = oj; }
      od = __shfl_xor(bd1[r], mm, 64); oj = __shfl_xor(jl1[r], mm, 64);
      if (od < bd1[r] || (od == bd1[r] && oj < jl1[r])) { bd1[r] = od; jl1[r] = oj; }
    }
  }
  if (col == 0) {
    #pragma unroll
    for (int r = 0; r < 4; ++r) {
      const int pA = p0 + quad * 4 + r;
      pd[(long)pA * SCH + cid] = bd0[r];
      pi[(long)pA * SCH + cid] = jb + jl0[r];
      const int pB = pA + 16;
      pd[(long)pB * SCH + cid] = bd1[r];
      pi[(long)pB * SCH + cid] = jb + jl1[r];
    }
  }
}

// ---------------- exact-fp32 rescue + argmin finalize + zq gather + loss ----------------
__global__ __launch_bounds__(256) void k_rescue(
    const float* __restrict__ zc, const float* __restrict__ cb,
    const float* __restrict__ cnorm,
    const float* __restrict__ pd, const int* __restrict__ pi,
    float* __restrict__ zq, float* __restrict__ lpart) {
  const int lane = threadIdx.x & 63;
  const int wv   = threadIdx.x >> 6;
  const int p    = blockIdx.x * 4 + wv;

  const float m = pd[(long)p * SCH + lane];
  float dstar = m;
  #pragma unroll
  for (int mm = 1; mm <= 32; mm <<= 1) dstar = fminf(dstar, __shfl_xor(dstar, mm, 64));
  unsigned long long mask = __ballot(m <= dstar + MARGIN);

  float zr[CD];
  {
    const float4* z4 = (const float4*)(zc + (long)p * CD);
    #pragma unroll
    for (int q = 0; q < 8; ++q) {
      float4 v = z4[q];
      zr[4 * q + 0] = v.x; zr[4 * q + 1] = v.y; zr[4 * q + 2] = v.z; zr[4 * q + 3] = v.w;
    }
  }

  float bd = 1e30f;
  int   bj = 0x7fffffff;
  while (mask) {
    const int c = (int)__builtin_ctzll(mask);
    mask &= mask - 1;
    #pragma unroll
    for (int u = 0; u < 2; ++u) {
      const int j = c * CPC + u * 64 + lane;
      const float4* crow = (const float4*)(cb + (long)j * CD);
      float acc = 0.f;
      #pragma unroll
      for (int q = 0; q < 8; ++q) {
        float4 cv = crow[q];
        acc = fmaf(zr[4 * q + 0], cv.x, acc);
        acc = fmaf(zr[4 * q + 1], cv.y, acc);
        acc = fmaf(zr[4 * q + 2], cv.z, acc);
        acc = fmaf(zr[4 * q + 3], cv.w, acc);
      }
      const float d = fmaf(-2.f, acc, cnorm[j]);
      if (d < bd) { bd = d; bj = j; }
    }
  }
  #pragma unroll
  for (int mm = 1; mm <= 32; mm <<= 1) {
    const float od = __shfl_xor(bd, mm, 64);
    const int   oj = __shfl_xor(bj, mm, 64);
    if (od < bd || (od == bd && oj < bj)) { bd = od; bj = oj; }
  }

  float ls = 0.f;
  if (lane < 32) {
    const float cv = cb[(long)bj * CD + lane];
    const float zv = zc[(long)p * CD + lane];
    zq[(long)p * CD + lane] = cv;
    const float df = cv - zv;
    ls = df * df;
  }
  #pragma unroll
  for (int mm = 1; mm <= 32; mm <<= 1) ls += __shfl_xor(ls, mm, 64);
  if (lane == 0) lpart[p] = ls;
}

__global__ __launch_bounds__(1024) void k_loss(const float* __restrict__ lpart,
                                               float* __restrict__ out_loss) {
  __shared__ float red[16];
  const int t = threadIdx.x;
  float v = 0.f;
  for (int k = t; k < M; k += 1024) v += lpart[k];
  #pragma unroll
  for (int mm = 1; mm <= 32; mm <<= 1) v += __shfl_xor(v, mm, 64);
  if ((t & 63) == 0) red[t >> 6] = v;
  __syncthreads();
  if (t == 0) {
    float s = 0.f;
    #pragma unroll
    for (int i = 0; i < 16; ++i) s += red[i];
    out_loss[0] = 3.0f * s / (float)(M * CD);
  }
}

// ---------------- out = z_q @ W_expand + b_expand ----------------
// block = 16 rows (processed in pairs) x 256 cols; thread holds ONE W column
__global__ __launch_bounds__(256) void k_expand(
    const float* __restrict__ zq,
    const float* __restrict__ We,
    const float* __restrict__ be,
    float* __restrict__ out) {
  const int t  = threadIdx.x;
  const int rb = blockIdx.x & 1023;        // grid 3*1024
  const int g  = blockIdx.x >> 10;         // 0..2
  const int c  = g * 256 + t;
  const int r0 = rb * 16;
  float w[CD];
  #pragma unroll
  for (int k = 0; k < CD; ++k) w[k] = We[k * CIN + c];
  const float bb = be[c];
  #pragma unroll 2
  for (int r = r0; r < r0 + 16; r += 2) {
    const float4* qa = (const float4*)(zq + (long)r * CD);
    const float4* qb = (const float4*)(zq + (long)(r + 1) * CD);
    float a0 = bb, a1 = bb;
    #pragma unroll
    for (int k4 = 0; k4 < 8; ++k4) {
      const float4 va = qa[k4];
      const float4 vb = qb[k4];
      a0 = fmaf(va.x, w[4 * k4 + 0], a0);
      a1 = fmaf(vb.x, w[4 * k4 + 0], a1);
      a0 = fmaf(va.y, w[4 * k4 + 1], a0);
      a1 = fmaf(vb.y, w[4 * k4 + 1], a1);
      a0 = fmaf(va.z, w[4 * k4 + 2], a0);
      a1 = fmaf(vb.z, w[4 * k4 + 2], a1);
      a0 = fmaf(va.w, w[4 * k4 + 3], a0);
      a1 = fmaf(vb.w, w[4 * k4 + 3], a1);
    }
    out[(long)r * CIN + c]       = a0;
    out[(long)(r + 1) * CIN + c] = a1;
  }
}

extern "C" void kernel_launch(void* const* d_in, const int* in_sizes, int n_in,
                              void* d_out, int out_size, void* d_ws, size_t ws_size,
                              hipStream_t stream) {
  const float* z   = (const float*)d_in[0];
  const float* emb = (const float*)d_in[1];
  const float* Wc  = (const float*)d_in[2];
  const float* bc  = (const float*)d_in[3];
  const float* Wct = (const float*)d_in[4];
  const float* bct = (const float*)d_in[5];
  const float* We  = (const float*)d_in[6];
  const float* be  = (const float*)d_in[7];
  float* out = (float*)d_out;

  float* cb    = (float*)d_ws;              // NE*CD        = 262144 f
  float* cnorm = cb + NE * CD;              // NE           = 8192 f
  float* zc    = cnorm + NE;                // M*CD         = 524288 f
  float* zq    = zc + M * CD;               // M*CD         = 524288 f
  float* pd    = zq + M * CD;               // M*SCH        = 1048576 f
  float* lpart = pd + (long)M * SCH;        // M            = 16384 f
  int*   pi    = (int*)(lpart + M);         // M*SCH        = 1048576 i
  unsigned short* zh = (unsigned short*)(pi + (long)M * SCH);  // M*CD ushort
  unsigned short* zl = zh + M * CD;
  unsigned short* ch = zl + M * CD;         // NE*CD ushort
  unsigned short* cl = ch + NE * CD;

  k_codebook<<<NE * CD / 256, 256, 0, stream>>>(emb, Wct, bct, cb, cnorm, ch, cl);
  k_compress<<<M / 32, 256, 0, stream>>>(z, Wc, bc, zc, zh, zl);
  k_argmin<<<(M / PTB) * SCH, 256, 0, stream>>>(zh, zl, ch, cl, cnorm, pd, pi);
  k_rescue<<<M / 4, 256, 0, stream>>>(zc, cb, cnorm, pd, pi, zq, lpart);
  k_loss<<<1, 1024, 0, stream>>>(lpart, out + (long)M * CIN);
  k_expand<<<3 * 1024, 256, 0, stream>>>(zq, We, be, out);
}

// Round 6
// 278.251 us; speedup vs baseline: 2.1926x; 1.0269x over previous
//
#include <hip/hip_runtime.h>

constexpr int CIN = 768;
constexpr int CD  = 32;
constexpr int NE  = 8192;
constexpr int M   = 16384;      // B*N = 64*256
constexpr int SCH = 64;         // code chunks for argmin
constexpr int CPC = NE / SCH;   // 128 codes per chunk
constexpr int PTB = 128;        // points per argmin block (4 waves x 32)
#define MARGIN 0.05f

typedef short short8 __attribute__((ext_vector_type(8)));
typedef float f32x4  __attribute__((ext_vector_type(4)));

// RNE split of fp32 into bf16 hi + bf16 lo-residual
__device__ inline void split_bf16(float x, unsigned short& h, unsigned short& l) {
  unsigned u = __float_as_uint(x);
  unsigned hb = (u + 0x7FFFu + ((u >> 16) & 1u)) >> 16;
  float hf = __uint_as_float(hb << 16);
  float r = x - hf;
  unsigned u2 = __float_as_uint(r);
  unsigned lb = (u2 + 0x7FFFu + ((u2 >> 16) & 1u)) >> 16;
  h = (unsigned short)hb;
  l = (unsigned short)lb;
}

// ---------------- fused: codebook (blocks 0..1023) + K-split compress (1024..3071) ----
// compress: block = 8 rows x 32 cols x 4 K-groups (K-split x4, LDS reduce)
__global__ __launch_bounds__(256, 6) void k_pre(
    const float* __restrict__ emb, const float* __restrict__ Wct,
    const float* __restrict__ bct,
    const float* __restrict__ z, const float* __restrict__ Wc,
    const float* __restrict__ bc,
    float* __restrict__ cb, float* __restrict__ cnorm,
    unsigned short* __restrict__ ch, unsigned short* __restrict__ cl,
    float* __restrict__ zc, unsigned short* __restrict__ zh,
    unsigned short* __restrict__ zl) {
  __shared__ float smem[1024];
  const int t = threadIdx.x;
  if (blockIdx.x < 1024) {
    // ---- codebook = emb @ W_ct + b_ct ----
    for (int i = t; i < CD * CD; i += 256) smem[i] = Wct[i];
    __syncthreads();
    const int g   = blockIdx.x * 256 + t;
    const int row = g >> 5;
    const int col = g & 31;
    float acc = bct[col];
    const float* er = emb + row * CD;
    #pragma unroll
    for (int k = 0; k < CD; ++k) acc = fmaf(er[k], smem[k * CD + col], acc);
    cb[g] = acc;
    unsigned short h, l;
    split_bf16(acc, h, l);
    ch[g] = h; cl[g] = l;
    float v = acc * acc;
    #pragma unroll
    for (int m = 16; m >= 1; m >>= 1) v += __shfl_xor(v, m, 64);
    if (col == 0) cnorm[row] = v;
  } else {
    // ---- zc = z @ W_compress + b (K-split x4) ----
    const int bid  = blockIdx.x - 1024;       // 0..2047
    const int kg   = t >> 6;                  // 0..3
    const int rloc = (t >> 3) & 7;            // 0..7
    const int c0   = (t & 7) * 4;
    const int row  = bid * 8 + rloc;
    const float4* zr = (const float4*)(z + (long)row * CIN);
    float4 acc;
    if (kg == 0) acc = *(const float4*)(bc + c0);
    else         acc = make_float4(0.f, 0.f, 0.f, 0.f);
    int k4 = kg * 48;
    // depth-1 register prefetch pipeline
    float4 zv = zr[k4];
    float4 w0 = *(const float4*)(Wc + (k4 * 4 + 0) * CD + c0);
    float4 w1 = *(const float4*)(Wc + (k4 * 4 + 1) * CD + c0);
    float4 w2 = *(const float4*)(Wc + (k4 * 4 + 2) * CD + c0);
    float4 w3 = *(const float4*)(Wc + (k4 * 4 + 3) * CD + c0);
    for (int i = 0; i < 48; ++i) {
      const int kn = (i == 47) ? k4 : k4 + 1;
      const float4 zn = zr[kn];
      const float4 n0 = *(const float4*)(Wc + (kn * 4 + 0) * CD + c0);
      const float4 n1 = *(const float4*)(Wc + (kn * 4 + 1) * CD + c0);
      const float4 n2 = *(const float4*)(Wc + (kn * 4 + 2) * CD + c0);
      const float4 n3 = *(const float4*)(Wc + (kn * 4 + 3) * CD + c0);
      acc.x = fmaf(zv.x, w0.x, acc.x);
      acc.y = fmaf(zv.x, w0.y, acc.y);
      acc.z = fmaf(zv.x, w0.z, acc.z);
      acc.w = fmaf(zv.x, w0.w, acc.w);
      acc.x = fmaf(zv.y, w1.x, acc.x);
      acc.y = fmaf(zv.y, w1.y, acc.y);
      acc.z = fmaf(zv.y, w1.z, acc.z);
      acc.w = fmaf(zv.y, w1.w, acc.w);
      acc.x = fmaf(zv.z, w2.x, acc.x);
      acc.y = fmaf(zv.z, w2.y, acc.y);
      acc.z = fmaf(zv.z, w2.z, acc.z);
      acc.w = fmaf(zv.z, w2.w, acc.w);
      acc.x = fmaf(zv.w, w3.x, acc.x);
      acc.y = fmaf(zv.w, w3.y, acc.y);
      acc.z = fmaf(zv.w, w3.z, acc.z);
      acc.w = fmaf(zv.w, w3.w, acc.w);
      zv = zn; w0 = n0; w1 = n1; w2 = n2; w3 = n3;
      ++k4;
    }
    // LDS reduce across the 4 K-groups (deterministic order)
    *(float4*)(smem + kg * 256 + rloc * 32 + c0) = acc;
    __syncthreads();
    if (kg == 0) {
      const int base = rloc * 32 + c0;
      float4 p0 = *(const float4*)(smem + base);
      float4 p1 = *(const float4*)(smem + 256 + base);
      float4 p2 = *(const float4*)(smem + 512 + base);
      float4 p3 = *(const float4*)(smem + 768 + base);
      float4 s;
      s.x = ((p0.x + p1.x) + p2.x) + p3.x;
      s.y = ((p0.y + p1.y) + p2.y) + p3.y;
      s.z = ((p0.z + p1.z) + p2.z) + p3.z;
      s.w = ((p0.w + p1.w) + p2.w) + p3.w;
      const long idx = (long)row * CD + c0;
      *(float4*)(zc + idx) = s;
      ushort4 h4, l4;
      split_bf16(s.x, h4.x, l4.x);
      split_bf16(s.y, h4.y, l4.y);
      split_bf16(s.z, h4.z, l4.z);
      split_bf16(s.w, h4.w, l4.w);
      *(ushort4*)(zh + idx) = h4;
      *(ushort4*)(zl + idx) = l4;
    }
  }
}

// ---------------- MFMA approx distances + per-chunk argmin ----------------
// grid = (M/PTB=128) x SCH=64 -> 8192 blocks; wave handles 32 points x 128 codes
__global__ __launch_bounds__(256) void k_argmin(
    const unsigned short* __restrict__ zh, const unsigned short* __restrict__ zl,
    const unsigned short* __restrict__ ch, const unsigned short* __restrict__ cl,
    const float* __restrict__ cnorm,
    float* __restrict__ pd, int* __restrict__ pi) {
  const int pb   = blockIdx.x & (M / PTB - 1);   // 0..127
  const int cid  = blockIdx.x >> 7;              // 0..63
  const int lane = threadIdx.x & 63;
  const int wv   = threadIdx.x >> 6;
  const int col  = lane & 15;
  const int quad = lane >> 4;
  const int p0   = pb * PTB + wv * 32;

  const short8 Ah0 = *(const short8*)(zh + (long)(p0 + col) * CD + quad * 8);
  const short8 Al0 = *(const short8*)(zl + (long)(p0 + col) * CD + quad * 8);
  const short8 Ah1 = *(const short8*)(zh + (long)(p0 + 16 + col) * CD + quad * 8);
  const short8 Al1 = *(const short8*)(zl + (long)(p0 + 16 + col) * CD + quad * 8);

  const int jb = cid * CPC;
  float bd0[4], bd1[4];
  int   bj0[4], bj1[4];
  #pragma unroll
  for (int r = 0; r < 4; ++r) { bd0[r] = 1e30f; bd1[r] = 1e30f; bj0[r] = 0; bj1[r] = 0; }

  for (int t = 0; t < CPC / 16; ++t) {           // 8 tiles of 16 codes
    const int cb0 = jb + t * 16;
    const short8 Bh = *(const short8*)(ch + (long)(cb0 + col) * CD + quad * 8);
    const short8 Bl = *(const short8*)(cl + (long)(cb0 + col) * CD + quad * 8);
    f32x4 g0 = {0.f, 0.f, 0.f, 0.f};
    f32x4 g1 = {0.f, 0.f, 0.f, 0.f};
    g0 = __builtin_amdgcn_mfma_f32_16x16x32_bf16(Ah0, Bh, g0, 0, 0, 0);
    g0 = __builtin_amdgcn_mfma_f32_16x16x32_bf16(Ah0, Bl, g0, 0, 0, 0);
    g0 = __builtin_amdgcn_mfma_f32_16x16x32_bf16(Al0, Bh, g0, 0, 0, 0);
    g1 = __builtin_amdgcn_mfma_f32_16x16x32_bf16(Ah1, Bh, g1, 0, 0, 0);
    g1 = __builtin_amdgcn_mfma_f32_16x16x32_bf16(Ah1, Bl, g1, 0, 0, 0);
    g1 = __builtin_amdgcn_mfma_f32_16x16x32_bf16(Al1, Bh, g1, 0, 0, 0);
    const float cnv = cnorm[cb0 + col];
    #pragma unroll
    for (int r = 0; r < 4; ++r) {
      const float d0 = fmaf(-2.f, g0[r], cnv);
      if (d0 < bd0[r]) { bd0[r] = d0; bj0[r] = t; }
      const float d1 = fmaf(-2.f, g1[r], cnv);
      if (d1 < bd1[r]) { bd1[r] = d1; bj1[r] = t; }
    }
  }

  int jl0[4], jl1[4];
  #pragma unroll
  for (int r = 0; r < 4; ++r) { jl0[r] = bj0[r] * 16 + col; jl1[r] = bj1[r] * 16 + col; }
  #pragma unroll
  for (int mm = 1; mm <= 8; mm <<= 1) {
    #pragma unroll
    for (int r = 0; r < 4; ++r) {
      float od = __shfl_xor(bd0[r], mm, 64); int oj = __shfl_xor(jl0[r], mm, 64);
      if (od < bd0[r] || (od == bd0[r] && oj < jl0[r])) { bd0[r] = od; jl0[r] = oj; }
      od = __shfl_xor(bd1[r], mm, 64); oj = __shfl_xor(jl1[r], mm, 64);
      if (od < bd1[r] || (od == bd1[r] && oj < jl1[r])) { bd1[r] = od; jl1[r] = oj; }
    }
  }
  if (col == 0) {
    #pragma unroll
    for (int r = 0; r < 4; ++r) {
      const int pA = p0 + quad * 4 + r;
      pd[(long)pA * SCH + cid] = bd0[r];
      pi[(long)pA * SCH + cid] = jb + jl0[r];
      const int pB = pA + 16;
      pd[(long)pB * SCH + cid] = bd1[r];
      pi[(long)pB * SCH + cid] = jb + jl1[r];
    }
  }
}

// ---------------- exact-fp32 rescue + argmin finalize + zq gather + loss partials ------
__global__ __launch_bounds__(256) void k_rescue(
    const float* __restrict__ zc, const float* __restrict__ cb,
    const float* __restrict__ cnorm,
    const float* __restrict__ pd, const int* __restrict__ pi,
    float* __restrict__ zq, float* __restrict__ lpart) {
  const int lane = threadIdx.x & 63;
  const int wv   = threadIdx.x >> 6;
  const int p    = blockIdx.x * 4 + wv;

  const float m = pd[(long)p * SCH + lane];
  float dstar = m;
  #pragma unroll
  for (int mm = 1; mm <= 32; mm <<= 1) dstar = fminf(dstar, __shfl_xor(dstar, mm, 64));
  unsigned long long mask = __ballot(m <= dstar + MARGIN);

  float zr[CD];
  {
    const float4* z4 = (const float4*)(zc + (long)p * CD);
    #pragma unroll
    for (int q = 0; q < 8; ++q) {
      float4 v = z4[q];
      zr[4 * q + 0] = v.x; zr[4 * q + 1] = v.y; zr[4 * q + 2] = v.z; zr[4 * q + 3] = v.w;
    }
  }

  float bd = 1e30f;
  int   bj = 0x7fffffff;
  while (mask) {
    const int c = (int)__builtin_ctzll(mask);
    mask &= mask - 1;
    #pragma unroll
    for (int u = 0; u < 2; ++u) {
      const int j = c * CPC + u * 64 + lane;
      const float4* crow = (const float4*)(cb + (long)j * CD);
      float acc = 0.f;
      #pragma unroll
      for (int q = 0; q < 8; ++q) {
        float4 cv = crow[q];
        acc = fmaf(zr[4 * q + 0], cv.x, acc);
        acc = fmaf(zr[4 * q + 1], cv.y, acc);
        acc = fmaf(zr[4 * q + 2], cv.z, acc);
        acc = fmaf(zr[4 * q + 3], cv.w, acc);
      }
      const float d = fmaf(-2.f, acc, cnorm[j]);
      if (d < bd) { bd = d; bj = j; }
    }
  }
  #pragma unroll
  for (int mm = 1; mm <= 32; mm <<= 1) {
    const float od = __shfl_xor(bd, mm, 64);
    const int   oj = __shfl_xor(bj, mm, 64);
    if (od < bd || (od == bd && oj < bj)) { bd = od; bj = oj; }
  }

  float ls = 0.f;
  if (lane < 32) {
    const float cv = cb[(long)bj * CD + lane];
    const float zv = zc[(long)p * CD + lane];
    zq[(long)p * CD + lane] = cv;
    const float df = cv - zv;
    ls = df * df;
  }
  #pragma unroll
  for (int mm = 1; mm <= 32; mm <<= 1) ls += __shfl_xor(ls, mm, 64);
  if (lane == 0) lpart[p] = ls;
}

// ---------------- out = z_q @ W_expand + b_expand ; block 3072 = loss reduce ----------
__global__ __launch_bounds__(256) void k_expand(
    const float* __restrict__ zq,
    const float* __restrict__ We,
    const float* __restrict__ be,
    const float* __restrict__ lpart,
    float* __restrict__ out,
    float* __restrict__ out_loss) {
  __shared__ float red[4];
  const int t = threadIdx.x;
  if (blockIdx.x == 3072) {
    float v = 0.f;
    for (int k = t; k < M; k += 256) v += lpart[k];
    #pragma unroll
    for (int mm = 1; mm <= 32; mm <<= 1) v += __shfl_xor(v, mm, 64);
    if ((t & 63) == 0) red[t >> 6] = v;
    __syncthreads();
    if (t == 0) out_loss[0] = 3.0f * (red[0] + red[1] + red[2] + red[3]) / (float)(M * CD);
    return;
  }
  const int rb = blockIdx.x & 1023;        // 1024 row-blocks
  const int g  = blockIdx.x >> 10;         // 0..2 col-groups
  const int c  = g * 256 + t;
  const int r0 = rb * 16;
  float w[CD];
  #pragma unroll
  for (int k = 0; k < CD; ++k) w[k] = We[k * CIN + c];
  const float bb = be[c];
  #pragma unroll 2
  for (int r = r0; r < r0 + 16; r += 2) {
    const float4* qa = (const float4*)(zq + (long)r * CD);
    const float4* qb = (const float4*)(zq + (long)(r + 1) * CD);
    float a0 = bb, a1 = bb;
    #pragma unroll
    for (int k4 = 0; k4 < 8; ++k4) {
      const float4 va = qa[k4];
      const float4 vb = qb[k4];
      a0 = fmaf(va.x, w[4 * k4 + 0], a0);
      a1 = fmaf(vb.x, w[4 * k4 + 0], a1);
      a0 = fmaf(va.y, w[4 * k4 + 1], a0);
      a1 = fmaf(vb.y, w[4 * k4 + 1], a1);
      a0 = fmaf(va.z, w[4 * k4 + 2], a0);
      a1 = fmaf(vb.z, w[4 * k4 + 2], a1);
      a0 = fmaf(va.w, w[4 * k4 + 3], a0);
      a1 = fmaf(vb.w, w[4 * k4 + 3], a1);
    }
    out[(long)r * CIN + c]       = a0;
    out[(long)(r + 1) * CIN + c] = a1;
  }
}

extern "C" void kernel_launch(void* const* d_in, const int* in_sizes, int n_in,
                              void* d_out, int out_size, void* d_ws, size_t ws_size,
                              hipStream_t stream) {
  const float* z   = (const float*)d_in[0];
  const float* emb = (const float*)d_in[1];
  const float* Wc  = (const float*)d_in[2];
  const float* bc  = (const float*)d_in[3];
  const float* Wct = (const float*)d_in[4];
  const float* bct = (const float*)d_in[5];
  const float* We  = (const float*)d_in[6];
  const float* be  = (const float*)d_in[7];
  float* out = (float*)d_out;

  float* cb    = (float*)d_ws;              // NE*CD        = 262144 f
  float* cnorm = cb + NE * CD;              // NE           = 8192 f
  float* zc    = cnorm + NE;                // M*CD         = 524288 f
  float* zq    = zc + M * CD;               // M*CD         = 524288 f
  float* pd    = zq + M * CD;               // M*SCH        = 1048576 f
  float* lpart = pd + (long)M * SCH;        // M            = 16384 f
  int*   pi    = (int*)(lpart + M);         // M*SCH        = 1048576 i
  unsigned short* zh = (unsigned short*)(pi + (long)M * SCH);  // M*CD ushort
  unsigned short* zl = zh + M * CD;
  unsigned short* ch = zl + M * CD;         // NE*CD ushort
  unsigned short* cl = ch + NE * CD;

  k_pre<<<3072, 256, 0, stream>>>(emb, Wct, bct, z, Wc, bc,
                                  cb, cnorm, ch, cl, zc, zh, zl);
  k_argmin<<<(M / PTB) * SCH, 256, 0, stream>>>(zh, zl, ch, cl, cnorm, pd, pi);
  k_rescue<<<M / 4, 256, 0, stream>>>(zc, cb, cnorm, pd, pi, zq, lpart);
  k_expand<<<3072 + 1, 256, 0, stream>>>(zq, We, be, lpart, out, out + (long)M * CIN);
}